// Round 7
// baseline (117232.764 us; speedup 1.0000x reference)
//
#include <hip/hip_runtime.h>

// ---------------------------------------------------------------------------
// TTS forward on MI355X.  Round 7: right-sized parallelism.
//   Encoder: 2 self-contained blocks (one per direction), h/c in LDS+regs,
//            ZERO inter-block synchronization.
//   Decoder: 8 persistent blocks (one per XCD), each owns 512 gate rows
//            (weights L2-resident), 8-flag sync, never-reused h ring.
// ---------------------------------------------------------------------------

typedef float f4 __attribute__((ext_vector_type(4)));
typedef _Float16 h8 __attribute__((ext_vector_type(8)));
typedef unsigned int u32x4 __attribute__((ext_vector_type(4)));
typedef _Float16 half_t;
typedef unsigned long long u64;

#define B_    32
#define LTXT  256
#define TMEL  800
#define EE    512
#define HH    512
#define DD    1024
#define MM    128
#define NROWS 8192          // B_*LTXT
#define GATE_OFF 3276800    // B_*TMEL*MM
#define MASK_OFF 3302400    // + B_*TMEL

#define RING_D 801          // decoder h ring slots (never reused in 800 steps)
#define HOP    13           // slot hop stride (coprime with RING_D)

// workspace offsets (bytes)
#define WS_FLAGS     0ull              // 8 x 64B dec flags (zeroed)
#define WS_ZERO_BYTES 4096ull
#define WS_HD        8192ull           // RING_D * 65536 = 52,494,336
#define WS_BUFX      52502528ull       // 8 MiB
#define WS_BUFY      60891136ull       // 8 MiB
#define WS_CONVF     69279744ull       // 16 MiB (reused by WEFF/W0 after convs)
#define WS_WEFF      69279744ull       // 8 MiB
#define WS_W0        77668352ull       // 8 MiB
#define WS_WP1       86056960ull
#define WS_WP2       87629824ull
#define WS_WIHP      89202688ull       // 4 MiB
#define WS_WHHP      93396992ull       // 4 MiB
#define WS_BSUM      97591296ull
#define WS_BEFF      97607680ull
#define WS_B0        97624064ull
#define WS_MEAN      97640448ull
#define WS_RSTD      97642496ull
#define WS_PROJW     97644544ull
#define WS_PROJG     97906688ull
#define WS_CEL       97939456ull
// total ~98.1 MB

__device__ __forceinline__ float sigm(float x) { return 1.f / (1.f + __expf(-x)); }
__device__ __forceinline__ float tanh_f(float x) {
    float e = __expf(2.f * x);
    return 1.f - 2.f / (e + 1.f);
}

// write-through stores (visible device-wide), non-atomic
__device__ __forceinline__ void st_wt128(void* p, u32x4 v) {
    asm volatile("global_store_dwordx4 %0, %1, off sc0 sc1" :: "v"(p), "v"(v) : "memory");
}
__device__ __forceinline__ void st_wt32(void* p, unsigned v) {
    asm volatile("global_store_dword %0, %1, off sc0 sc1" :: "v"(p), "v"(v) : "memory");
}

// wave-0 flag poll: lane i (lane_ok) watches flags[i*16]; exits when all >= tgt.
__device__ __forceinline__ void flag_wait(const unsigned* fp, int lane_ok, unsigned tgt) {
    for (;;) {
        unsigned v = lane_ok
            ? __hip_atomic_load(fp, __ATOMIC_RELAXED, __HIP_MEMORY_SCOPE_AGENT)
            : tgt;
        if (__all((int)(v >= tgt))) break;
    }
    __atomic_signal_fence(__ATOMIC_SEQ_CST);
}

// ---------------- small prep kernels ----------------

__global__ void k_embed(const int* __restrict__ x, const float* __restrict__ emb,
                        half_t* __restrict__ out) {
    int row = blockIdx.x;
    int tok = x[row];
    const float* e = emb + (size_t)tok * EE;
    half_t* o = out + (size_t)row * EE;
    for (int c = threadIdx.x; c < EE; c += blockDim.x) o[c] = (half_t)e[c];
}

__global__ void k_packconvw(const float* __restrict__ w, half_t* __restrict__ wp) {
    int idx = blockIdx.x * 256 + threadIdx.x;
    if (idx >= 3 * EE * EE) return;
    int s = idx / (EE * EE);
    int rem = idx - s * EE * EE;
    int eo = rem >> 9, ei = rem & 511;
    wp[idx] = (half_t)w[(size_t)eo * (EE * 3) + ei * 3 + s];
}

__global__ __launch_bounds__(256) void k_conv(const half_t* __restrict__ A,
                                              const half_t* __restrict__ Wp,
                                              const float* __restrict__ bias,
                                              float* __restrict__ out) {
    const int nt = blockIdx.x, et = blockIdx.y;
    const int tid = threadIdx.x;
    const int wv = tid >> 6, l = tid & 63, quad = l >> 4, lo = l & 15;
    const int rowA = nt * 64 + wv * 16 + lo;
    const int eo = et * 16 + lo;
    f4 acc = {0.f, 0.f, 0.f, 0.f};
    for (int s = 0; s < 3; ++s) {
        int lsp = (rowA & 255) + s - 1;
        bool valid = (lsp >= 0) && (lsp < 256);
        int rs = rowA + s - 1;
        rs = rs < 0 ? 0 : (rs > NROWS - 1 ? NROWS - 1 : rs);
        const half_t* ab = A + (size_t)rs * EE;
        const half_t* wb = Wp + ((size_t)s * EE + eo) * EE;
#pragma unroll 4
        for (int ks = 0; ks < 16; ++ks) {
            h8 a = {0, 0, 0, 0, 0, 0, 0, 0};
            if (valid) a = *(const h8*)(ab + ks * 32 + quad * 8);
            h8 b = *(const h8*)(wb + ks * 32 + quad * 8);
            acc = __builtin_amdgcn_mfma_f32_16x16x32_f16(a, b, acc, 0, 0, 0);
        }
    }
    const int orow = nt * 64 + wv * 16 + quad * 4;
    const float bv = bias[eo];
#pragma unroll
    for (int r = 0; r < 4; ++r) out[(size_t)(orow + r) * EE + eo] = acc[r] + bv;
}

__global__ __launch_bounds__(256) void k_bnstats(const float* __restrict__ x,
                                                 float* __restrict__ mean,
                                                 float* __restrict__ rstd) {
    const int c = blockIdx.x;
    float s = 0.f, ss = 0.f;
    for (int n = threadIdx.x; n < NROWS; n += 256) {
        float v = x[(size_t)n * EE + c];
        s += v; ss += v * v;
    }
#pragma unroll
    for (int off = 32; off > 0; off >>= 1) { s += __shfl_down(s, off); ss += __shfl_down(ss, off); }
    __shared__ float as[4], ass[4];
    int wv = threadIdx.x >> 6;
    if ((threadIdx.x & 63) == 0) { as[wv] = s; ass[wv] = ss; }
    __syncthreads();
    if (threadIdx.x == 0) {
        float S = as[0] + as[1] + as[2] + as[3];
        float SS = ass[0] + ass[1] + ass[2] + ass[3];
        float m = S / (float)NROWS;
        float var = SS / (float)NROWS - m * m;
        mean[c] = m;
        rstd[c] = rsqrtf(var + 1e-5f);
    }
}

__global__ void k_bnapply(const float* __restrict__ x, const float* __restrict__ mean,
                          const float* __restrict__ rstd, const float* __restrict__ g,
                          const float* __restrict__ beta, half_t* __restrict__ out) {
    int idx = blockIdx.x * 256 + threadIdx.x;
    if (idx >= NROWS * EE) return;
    int c = idx & (EE - 1);
    float v = (x[idx] - mean[c]) * rstd[c] * g[c] + beta[c];
    out[idx] = (half_t)(v > 0.f ? v : 0.f);
}

__global__ void k_packrec(const float* __restrict__ src, half_t* __restrict__ dst,
                          int Hdim, int kshift, int total) {
    int idx = blockIdx.x * 256 + threadIdx.x;
    if (idx >= total) return;
    int p = idx >> kshift;
    int k = idx & ((1 << kshift) - 1);
    int he = p >> 2, g = p & 3;
    dst[idx] = (half_t)src[((size_t)g * Hdim + he) * (size_t)(1 << kshift) + k];
}

__global__ void k_bsumenc(const float* __restrict__ bf, const float* __restrict__ bhf,
                          const float* __restrict__ bb, const float* __restrict__ bhb,
                          float* __restrict__ bsum) {
    int p = blockIdx.x * 256 + threadIdx.x;
    if (p >= 4096) return;
    int dir = p >> 11, pp = p & 2047;
    int he = pp >> 2, g = pp & 3;
    int row = g * HH + he;
    bsum[p] = dir ? (bb[row] + bhb[row]) : (bf[row] + bhf[row]);
}

__global__ __launch_bounds__(256) void k_weff(const float* __restrict__ dwhh,
                                              const float* __restrict__ dwih,
                                              const float* __restrict__ projw,
                                              half_t* __restrict__ weff,
                                              half_t* __restrict__ w0) {
    int row = blockIdx.x;
    int k = blockIdx.y * 256 + threadIdx.x;
    float v = dwhh[(size_t)row * DD + k];
    float acc = v;
    for (int m = 0; m < MM; ++m) acc += dwih[(size_t)row * MM + m] * projw[(size_t)m * DD + k];
    int p = ((row & (DD - 1)) << 2) | (row >> 10);
    weff[(size_t)p * DD + k] = (half_t)acc;
    w0[(size_t)p * DD + k] = (half_t)v;
}

__global__ void k_bdec(const float* __restrict__ dbih, const float* __restrict__ dbhh,
                       const float* __restrict__ dwih, const float* __restrict__ projb,
                       float* __restrict__ beff, float* __restrict__ b0) {
    int p = blockIdx.x * 256 + threadIdx.x;
    if (p >= 4096) return;
    int he = p >> 2, g = p & 3;
    int row = g * DD + he;
    float bb = dbih[row] + dbhh[row];
    float acc = bb;
    for (int m = 0; m < MM; ++m) acc += dwih[(size_t)row * MM + m] * projb[m];
    b0[p] = bb;
    beff[p] = acc;
}

__global__ void k_cast(const float* __restrict__ src, half_t* __restrict__ dst, int n) {
    int idx = blockIdx.x * 256 + threadIdx.x;
    if (idx < n) dst[idx] = (half_t)src[idx];
}

__global__ void k_projg(const float* __restrict__ gw, half_t* __restrict__ pg) {
    int idx = blockIdx.x * 256 + threadIdx.x;
    if (idx >= 16 * DD) return;
    int row = idx >> 10, k = idx & (DD - 1);
    pg[idx] = (half_t)(row == 0 ? gw[k] : 0.f);
}

__global__ void k_mask(const int* __restrict__ lens, float* __restrict__ out) {
    int idx = blockIdx.x * 256 + threadIdx.x;
    if (idx >= B_ * TMEL) return;
    int b = idx / TMEL, t = idx - b * TMEL;
    out[MASK_OFF + idx] = (t > lens[b]) ? 1.f : 0.f;
}

// ---------------- encoder: 2 self-contained blocks (one per direction) -----
// 512 thr, 8 waves = (rg 0..3) x (bh 0..1). Wave (rg,bh) owns 32 row-tiles
// (prows rg*512 + rt*16 + lo), batch half bh. h in LDS (pad 520), c in regs.
// One __syncthreads per step; NO inter-block sync.
__global__ __launch_bounds__(512, 2) void k_enc2(const half_t* __restrict__ X,
                                                 const half_t* __restrict__ wihp,
                                                 const half_t* __restrict__ whhp,
                                                 const float* __restrict__ bsum,
                                                 const int* __restrict__ lens,
                                                 half_t* __restrict__ hd0,   // dec ring slot 0 [32][1024]
                                                 float* __restrict__ cel) {  // [32][1024]
    const int dir = blockIdx.x;
    const int tid = threadIdx.x;
    const int wv = tid >> 6, l = tid & 63, quad = l >> 4, lo = l & 15;
    const int rg = wv >> 1, bh = wv & 1;
    const int b = bh * 16 + lo;

    __shared__ half_t hbuf[2][32 * 520];   // 66,560 B
    __shared__ float cbuf[32 * 516];       // 66,048 B
    __shared__ float scr[8][16][17];       // 8,704 B
    __shared__ int s_len[32];

    if (tid < 32) s_len[tid] = lens[tid];
    for (int i = tid; i < 32 * 520; i += 512) hbuf[0][i] = (half_t)0.f;

    float creg[32];
#pragma unroll
    for (int i = 0; i < 32; ++i) creg[i] = 0.f;

    const half_t* wih0 = wihp + ((size_t)dir * 2048 + rg * 512 + lo) * 512 + quad * 8;
    const half_t* whh0 = whhp + ((size_t)dir * 2048 + rg * 512 + lo) * 512 + quad * 8;
    const float* bs0 = bsum + dir * 2048 + rg * 512 + lo;

    __syncthreads();
    int par = 0;
    const int lb = s_len[b];

    for (int t = 0; t < 256; ++t) {
        int tt = dir ? (lb - 1 - t) : t;
        tt = tt < 0 ? 0 : tt;
        const half_t* xr = X + ((size_t)b * 256 + tt) * 512 + quad * 8;
        const half_t* hr = hbuf[par] + (size_t)b * 520 + quad * 8;
        h8 ah[16], ax[16];
#pragma unroll
        for (int ks = 0; ks < 16; ++ks) ah[ks] = *(const h8*)(hr + ks * 32);
#pragma unroll
        for (int ks = 0; ks < 16; ++ks) ax[ks] = *(const h8*)(xr + ks * 32);

        for (int rt = 0; rt < 32; ++rt) {
            const half_t* wa = wih0 + (size_t)rt * (16 * 512);
            const half_t* wb = whh0 + (size_t)rt * (16 * 512);
            f4 acc = {0.f, 0.f, 0.f, 0.f};
#pragma unroll
            for (int ks = 0; ks < 16; ++ks) {
                acc = __builtin_amdgcn_mfma_f32_16x16x32_f16(ax[ks], *(const h8*)(wa + ks * 32), acc, 0, 0, 0);
                acc = __builtin_amdgcn_mfma_f32_16x16x32_f16(ah[ks], *(const h8*)(wb + ks * 32), acc, 0, 0, 0);
            }
            const float bias = bs0[rt * 16];
#pragma unroll
            for (int r = 0; r < 4; ++r) scr[wv][lo][quad * 4 + r] = acc[r] + bias;
            // same-wave transpose read (compiler inserts lgkmcnt)
            float gi = scr[wv][quad * 4 + 0][lo];
            float gf = scr[wv][quad * 4 + 1][lo];
            float gg = scr[wv][quad * 4 + 2][lo];
            float go = scr[wv][quad * 4 + 3][lo];
            float cn = sigm(gf) * creg[rt] + sigm(gi) * tanh_f(gg);
            float hn = sigm(go) * tanh_f(cn);
            const int he = rg * 128 + rt * 4 + quad;
            float hout;
            if (t < lb) { creg[rt] = cn; hout = hn; }
            else        { hout = (float)hbuf[par][(size_t)b * 520 + he]; }
            hbuf[par ^ 1][(size_t)b * 520 + he] = (half_t)hout;
            if (t == 255) cbuf[b * 516 + he] = creg[rt];
        }
        __syncthreads();
        par ^= 1;
    }
    // export final h (-> decoder ring slot 0) and c
    const int bb = tid & 31;
    for (int he = tid >> 5; he < 512; he += 16) {
        hd0[(size_t)bb * 1024 + dir * 512 + he] = hbuf[par][(size_t)bb * 520 + he];
        cel[(size_t)bb * 1024 + dir * 512 + he] = cbuf[bb * 516 + he];
    }
}

// ---------------- decoder: 8 persistent blocks ------------------------------
// Block j owns prows [512j,512j+512) = h-elems [128j,128j+128). Wave (rg,bh)
// computes 8 row-tiles x batch-half. Weights (1MB/block) stay L2-resident.
// Update: thread (ub=tid&31, heg=tid>>5) owns 8 consecutive h-elems -> one
// 16B write-through store into the never-reused ring slot. 8-flag sync.
__global__ __launch_bounds__(512, 2) void k_dec8(const half_t* __restrict__ Weff,
                                                 const half_t* __restrict__ W0,
                                                 const float* __restrict__ beff,
                                                 const float* __restrict__ b0,
                                                 const half_t* __restrict__ projwb,
                                                 const half_t* __restrict__ projg,
                                                 const float* __restrict__ projb,
                                                 const float* __restrict__ gateb,
                                                 const int* __restrict__ mlens,
                                                 const float* __restrict__ cel,
                                                 half_t* __restrict__ hd,   // ring [RING_D][32][1024]
                                                 float* __restrict__ out,
                                                 unsigned* __restrict__ flags) {
    const int j = blockIdx.x;
    const int tid = threadIdx.x;
    const int wv = tid >> 6, l = tid & 63, quad = l >> 4, lo = l & 15;
    const int rg = wv >> 1, bh = wv & 1;
    const int ub = tid & 31, heg = tid >> 5;
    const unsigned* fp = flags + (size_t)l * 16;

    __shared__ float s_g[32][516];   // 66 KB
    __shared__ int s_len[32];

    if (tid < 32) s_len[tid] = mlens[tid];

    float cq[8];
#pragma unroll
    for (int q = 0; q < 8; ++q)
        cq[q] = cel[(size_t)ub * 1024 + j * 128 + heg * 8 + q];

    float er[8], zr[8];
#pragma unroll
    for (int rt = 0; rt < 8; ++rt) {
        er[rt] = beff[j * 512 + rg * 128 + rt * 16 + lo];
        zr[rt] = b0[j * 512 + rg * 128 + rt * 16 + lo];
    }
    const size_t wofs = ((size_t)j * 512 + rg * 128 + lo) * 1024 + quad * 8;
    const half_t* wE = Weff + wofs;
    const half_t* w0p = W0 + wofs;
    const bool melw = (rg == 0);            // mel tile j (every block)
    const bool gtw = (j == 0 && rg == 1);   // gate tile (block 0)
    const half_t* pw = projwb + ((size_t)j * 16 + lo) * 1024 + quad * 8;
    const half_t* pg = projg + (size_t)lo * 1024 + quad * 8;
    const float biasP = projb[j * 16 + lo];
    const float biasG = gateb[0];

    int sp = 0, sn = HOP;
    __syncthreads();

    for (int t = 1; t <= TMEL; ++t) {
        if (t >= 2 && wv == 0) flag_wait(fp, l < 8, (unsigned)(t - 1));
        __syncthreads();

        const half_t* ar = hd + (size_t)sp * 32768 + (size_t)(bh * 16 + lo) * 1024 + quad * 8;
        h8 af[32];
#pragma unroll
        for (int i = 0; i < 32; ++i) af[i] = *(const h8*)(ar + i * 32);

        const half_t* wsel = (t == 1) ? w0p : wE;
#pragma unroll
        for (int rt = 0; rt < 8; ++rt) {
            const half_t* wb = wsel + (size_t)rt * (16 * 1024);
            f4 acc = {0.f, 0.f, 0.f, 0.f};
#pragma unroll
            for (int ks = 0; ks < 32; ++ks)
                acc = __builtin_amdgcn_mfma_f32_16x16x32_f16(af[ks], *(const h8*)(wb + ks * 32), acc, 0, 0, 0);
            const float bias = (t == 1) ? zr[rt] : er[rt];
            const int pcol = rg * 128 + rt * 16 + lo;
#pragma unroll
            for (int r = 0; r < 4; ++r)
                s_g[bh * 16 + quad * 4 + r][pcol] = acc[r] + bias;
        }
        if (t >= 2) {
            if (melw) {
                f4 am = {0.f, 0.f, 0.f, 0.f};
#pragma unroll
                for (int ks = 0; ks < 32; ++ks)
                    am = __builtin_amdgcn_mfma_f32_16x16x32_f16(af[ks], *(const h8*)(pw + ks * 32), am, 0, 0, 0);
                const int pos = t - 2;
#pragma unroll
                for (int r = 0; r < 4; ++r) {
                    int bb = bh * 16 + quad * 4 + r;
                    float v = am[r] + biasP;
                    if (pos > s_len[bb]) v = 0.f;
                    __builtin_nontemporal_store(v,
                        &out[(size_t)bb * (TMEL * MM) + (size_t)pos * MM + j * 16 + lo]);
                }
            } else if (gtw) {
                f4 ag = {0.f, 0.f, 0.f, 0.f};
#pragma unroll
                for (int ks = 0; ks < 32; ++ks)
                    ag = __builtin_amdgcn_mfma_f32_16x16x32_f16(af[ks], *(const h8*)(pg + ks * 32), ag, 0, 0, 0);
                const int pos = t - 2;
                if (lo == 0) {
#pragma unroll
                    for (int r = 0; r < 4; ++r) {
                        int bb = bh * 16 + quad * 4 + r;
                        float v = ag[r] + biasG;
                        if (pos > s_len[bb]) v = 1000.f;
                        __builtin_nontemporal_store(v, &out[GATE_OFF + (size_t)bb * TMEL + pos]);
                    }
                }
            }
        }
        __syncthreads();
        // LSTM update: 8 consecutive h-elems per thread -> one 16B store
        union { half_t h[8]; u32x4 v; } pk;
#pragma unroll
        for (int q = 0; q < 8; ++q) {
            const float* gp = &s_g[ub][(heg * 8 + q) * 4];
            float gi = gp[0], gf = gp[1], gg = gp[2], go = gp[3];
            float cn = sigm(gf) * cq[q] + sigm(gi) * tanh_f(gg);
            cq[q] = cn;
            pk.h[q] = (half_t)(sigm(go) * tanh_f(cn));
        }
        st_wt128(hd + (size_t)sn * 32768 + (size_t)ub * 1024 + j * 128 + heg * 8, pk.v);
        __builtin_amdgcn_s_waitcnt(0);
        __syncthreads();
        if (tid == 0) st_wt32(flags + (size_t)j * 16, (unsigned)t);
        sp = sn; sn += HOP; if (sn >= RING_D) sn -= RING_D;
    }
    // epilogue: outputs for pos 799 from h_800 (slot sp)
    if (wv == 0) flag_wait(fp, l < 8, (unsigned)TMEL);
    __syncthreads();
    if (melw || gtw) {
        const half_t* ar = hd + (size_t)sp * 32768 + (size_t)(bh * 16 + lo) * 1024 + quad * 8;
        h8 af[32];
#pragma unroll
        for (int i = 0; i < 32; ++i) af[i] = *(const h8*)(ar + i * 32);
        f4 am = {0.f, 0.f, 0.f, 0.f};
        const half_t* pb = melw ? pw : pg;
#pragma unroll
        for (int ks = 0; ks < 32; ++ks)
            am = __builtin_amdgcn_mfma_f32_16x16x32_f16(af[ks], *(const h8*)(pb + ks * 32), am, 0, 0, 0);
        if (melw) {
#pragma unroll
            for (int r = 0; r < 4; ++r) {
                int bb = bh * 16 + quad * 4 + r;
                float v = am[r] + biasP;
                if (799 > s_len[bb]) v = 0.f;
                out[(size_t)bb * (TMEL * MM) + (size_t)799 * MM + j * 16 + lo] = v;
            }
        } else if (lo == 0) {
#pragma unroll
            for (int r = 0; r < 4; ++r) {
                int bb = bh * 16 + quad * 4 + r;
                float v = am[r] + biasG;
                if (799 > s_len[bb]) v = 1000.f;
                out[GATE_OFF + (size_t)bb * TMEL + 799] = v;
            }
        }
    }
}

// ---------------------------------------------------------------------------

extern "C" void kernel_launch(void* const* d_in, const int* in_sizes, int n_in,
                              void* d_out, int out_size, void* d_ws, size_t ws_size,
                              hipStream_t stream) {
    const int* x = (const int*)d_in[0];
    const int* tlens = (const int*)d_in[1];
    const int* mlens = (const int*)d_in[3];
    const float* emb = (const float*)d_in[4];
    const float* c1w = (const float*)d_in[5];
    const float* c1b = (const float*)d_in[6];
    const float* bn1g = (const float*)d_in[7];
    const float* bn1b = (const float*)d_in[8];
    const float* c2w = (const float*)d_in[9];
    const float* c2b = (const float*)d_in[10];
    const float* bn2g = (const float*)d_in[11];
    const float* bn2b = (const float*)d_in[12];
    const float* wihf = (const float*)d_in[13];
    const float* whhf = (const float*)d_in[14];
    const float* bihf = (const float*)d_in[15];
    const float* bhhf = (const float*)d_in[16];
    const float* wihb = (const float*)d_in[17];
    const float* whhb = (const float*)d_in[18];
    const float* bihb = (const float*)d_in[19];
    const float* bhhb = (const float*)d_in[20];
    const float* dwih = (const float*)d_in[21];
    const float* dwhh = (const float*)d_in[22];
    const float* dbih = (const float*)d_in[23];
    const float* dbhh = (const float*)d_in[24];
    const float* projw = (const float*)d_in[25];
    const float* projb = (const float*)d_in[26];
    const float* gatew = (const float*)d_in[27];
    const float* gateb = (const float*)d_in[28];
    float* out = (float*)d_out;
    char* ws = (char*)d_ws;

    unsigned* flags_dec = (unsigned*)(ws + WS_FLAGS);
    half_t* hd = (half_t*)(ws + WS_HD);
    half_t* bufX = (half_t*)(ws + WS_BUFX);
    half_t* bufY = (half_t*)(ws + WS_BUFY);
    float* convf = (float*)(ws + WS_CONVF);
    half_t* weff = (half_t*)(ws + WS_WEFF);
    half_t* w0 = (half_t*)(ws + WS_W0);
    half_t* wp1 = (half_t*)(ws + WS_WP1);
    half_t* wp2 = (half_t*)(ws + WS_WP2);
    half_t* wihp = (half_t*)(ws + WS_WIHP);
    half_t* whhp = (half_t*)(ws + WS_WHHP);
    float* bsum = (float*)(ws + WS_BSUM);
    float* beff = (float*)(ws + WS_BEFF);
    float* b0 = (float*)(ws + WS_B0);
    float* meanb = (float*)(ws + WS_MEAN);
    float* rstdb = (float*)(ws + WS_RSTD);
    half_t* projwb = (half_t*)(ws + WS_PROJW);
    half_t* projg = (half_t*)(ws + WS_PROJG);
    float* cel = (float*)(ws + WS_CEL);

    // zero decoder flags
    hipMemsetAsync(d_ws, 0, (size_t)WS_ZERO_BYTES, stream);

    // front-end
    k_embed<<<NROWS, 256, 0, stream>>>(x, emb, bufX);
    k_packconvw<<<(3 * EE * EE + 255) / 256, 256, 0, stream>>>(c1w, wp1);
    k_conv<<<dim3(128, 32), 256, 0, stream>>>(bufX, wp1, c1b, convf);
    k_bnstats<<<EE, 256, 0, stream>>>(convf, meanb, rstdb);
    k_bnapply<<<(NROWS * EE) / 256, 256, 0, stream>>>(convf, meanb, rstdb, bn1g, bn1b, bufY);
    k_packconvw<<<(3 * EE * EE + 255) / 256, 256, 0, stream>>>(c2w, wp2);
    k_conv<<<dim3(128, 32), 256, 0, stream>>>(bufY, wp2, c2b, convf);
    k_bnstats<<<EE, 256, 0, stream>>>(convf, meanb, rstdb);
    k_bnapply<<<(NROWS * EE) / 256, 256, 0, stream>>>(convf, meanb, rstdb, bn2g, bn2b, bufX);

    // encoder weight prep
    const int encTot = 2048 * 512;
    k_packrec<<<(encTot + 255) / 256, 256, 0, stream>>>(wihf, wihp, HH, 9, encTot);
    k_packrec<<<(encTot + 255) / 256, 256, 0, stream>>>(wihb, wihp + encTot, HH, 9, encTot);
    k_packrec<<<(encTot + 255) / 256, 256, 0, stream>>>(whhf, whhp, HH, 9, encTot);
    k_packrec<<<(encTot + 255) / 256, 256, 0, stream>>>(whhb, whhp + encTot, HH, 9, encTot);
    k_bsumenc<<<16, 256, 0, stream>>>(bihf, bhhf, bihb, bhhb, bsum);

    // self-contained bidirectional encoder (writes hd ring slot 0 + cel)
    k_enc2<<<2, 512, 0, stream>>>(bufX, wihp, whhp, bsum, tlens, hd, cel);

    // decoder weight prep (into retired convf region)
    k_weff<<<dim3(4096, 4), 256, 0, stream>>>(dwhh, dwih, projw, weff, w0);
    k_bdec<<<16, 256, 0, stream>>>(dbih, dbhh, dwih, projb, beff, b0);
    k_cast<<<(MM * DD + 255) / 256, 256, 0, stream>>>(projw, projwb, MM * DD);
    k_projg<<<(16 * DD + 255) / 256, 256, 0, stream>>>(gatew, projg);

    // persistent 8-block decoder
    k_dec8<<<8, 512, 0, stream>>>(weff, w0, beff, b0, projwb, projg, projb, gateb,
                                  mlens, cel, hd, out, flags_dec);

    // mask output
    k_mask<<<(B_ * TMEL + 255) / 256, 256, 0, stream>>>(mlens, out);

    (void)in_sizes; (void)n_in; (void)out_size; (void)ws_size;
}

// Round 8
// 17801.289 us; speedup vs baseline: 6.5856x; 6.5856x over previous
//
#include <hip/hip_runtime.h>

// ---------------------------------------------------------------------------
// TTS forward on MI355X.  Round 8 = Round 6 structure + anti-DVFS busy-spin.
//   - 64-block persistent enc (2 flag domains) / dec (1 domain), flag sync,
//     never-reused h rings, register A-prefetch (nontemporal).
//   - ALL waves spin actively (wave0: global flag poll + VALU burn; waves 1-7:
//     LDS release-word spin + VALU burn) to keep SCLK boosted.
//   - mel/gate output MFMA moved AFTER flag publish (off critical path).
//   - 4 independent MFMA accumulator chains for the gate GEMM.
// ---------------------------------------------------------------------------

typedef float f4 __attribute__((ext_vector_type(4)));
typedef _Float16 h8 __attribute__((ext_vector_type(8)));
typedef _Float16 half_t;
typedef unsigned long long u64;

#define B_    32
#define LTXT  256
#define TMEL  800
#define EE    512
#define HH    512
#define DD    1024
#define MM    128
#define NROWS 8192          // B_*LTXT
#define GATE_OFF 3276800    // B_*TMEL*MM
#define MASK_OFF 3302400    // + B_*TMEL

#define RING_D 801          // decoder h ring slots (never reused in 800 steps)
#define RING_E 257          // encoder h ring slots
#define HOP    13           // slot hop stride (coprime with both rings)

// workspace offsets (bytes)
#define WS_FLAGS     0ull              // dec @0 (4KB), encF @4096, encB @6144
#define WS_HENC      32768ull          // RING_E * 65536
#define WS_ZERO_BYTES 98304ull         // flags + henc slot 0
#define WS_HD        16875520ull       // RING_D * 65536
#define WS_BUFX      69369856ull       // 8 MiB
#define WS_BUFY      77758464ull       // 8 MiB
#define WS_CONVF     86147072ull       // 16 MiB (reused by WEFF/W0 after convs)
#define WS_WEFF      86147072ull
#define WS_W0        94535680ull
#define WS_WP1       102924288ull
#define WS_WP2       104497152ull
#define WS_WIHP      106070016ull      // 4 MiB
#define WS_WHHP      110264320ull      // 4 MiB
#define WS_BSUM      114458624ull
#define WS_BEFF      114475008ull
#define WS_B0        114491392ull
#define WS_MEAN      114507776ull
#define WS_RSTD      114509824ull
#define WS_PROJW     114511872ull
#define WS_PROJG     114774016ull
#define WS_CEL       114806784ull
// total ~114.9 MB

__device__ __forceinline__ float sigm(float x) { return 1.f / (1.f + __expf(-x)); }
__device__ __forceinline__ float tanh_f(float x) {
    float e = __expf(2.f * x);
    return 1.f - 2.f / (e + 1.f);
}

// write-through stores (land at the L3 coherence point), non-atomic
__device__ __forceinline__ void st_wt64(void* p, u64 v) {
    asm volatile("global_store_dwordx2 %0, %1, off sc0 sc1" :: "v"(p), "v"(v) : "memory");
}
__device__ __forceinline__ void st_wt32(void* p, unsigned v) {
    asm volatile("global_store_dword %0, %1, off sc0 sc1" :: "v"(p), "v"(v) : "memory");
}

// wave-0 flag poll with VALU burn: lane i watches flags[i*16].
__device__ __forceinline__ void flag_wait(const unsigned* fp, int lane_ok, unsigned tgt,
                                          float* burn) {
    float x = *burn;
    for (;;) {
        unsigned v = lane_ok
            ? __hip_atomic_load(fp, __ATOMIC_RELAXED, __HIP_MEMORY_SCOPE_AGENT)
            : tgt;
        x = __builtin_fmaf(x, 1.0000001f, 1e-7f);
        if (__all((int)(v >= tgt))) break;
    }
    *burn = x;
    __atomic_signal_fence(__ATOMIC_SEQ_CST);
}

// waves 1..7: spin on LDS release word with VALU burn
__device__ __forceinline__ void rel_spin(unsigned* s_rel, unsigned tgt, float* burn) {
    float x = *burn;
    while (__hip_atomic_load(s_rel, __ATOMIC_RELAXED, __HIP_MEMORY_SCOPE_WORKGROUP) < tgt) {
        x = __builtin_fmaf(x, 1.0000001f, 1e-7f);
        x = __builtin_fmaf(x, 1.0000001f, 1e-7f);
    }
    *burn = x;
    __atomic_signal_fence(__ATOMIC_SEQ_CST);
}

// ---------------- small prep kernels ----------------

__global__ void k_embed(const int* __restrict__ x, const float* __restrict__ emb,
                        half_t* __restrict__ out) {
    int row = blockIdx.x;
    int tok = x[row];
    const float* e = emb + (size_t)tok * EE;
    half_t* o = out + (size_t)row * EE;
    for (int c = threadIdx.x; c < EE; c += blockDim.x) o[c] = (half_t)e[c];
}

__global__ void k_packconvw(const float* __restrict__ w, half_t* __restrict__ wp) {
    int idx = blockIdx.x * 256 + threadIdx.x;
    if (idx >= 3 * EE * EE) return;
    int s = idx / (EE * EE);
    int rem = idx - s * EE * EE;
    int eo = rem >> 9, ei = rem & 511;
    wp[idx] = (half_t)w[(size_t)eo * (EE * 3) + ei * 3 + s];
}

__global__ __launch_bounds__(256) void k_conv(const half_t* __restrict__ A,
                                              const half_t* __restrict__ Wp,
                                              const float* __restrict__ bias,
                                              float* __restrict__ out) {
    const int nt = blockIdx.x, et = blockIdx.y;
    const int tid = threadIdx.x;
    const int wv = tid >> 6, l = tid & 63, quad = l >> 4, lo = l & 15;
    const int rowA = nt * 64 + wv * 16 + lo;
    const int eo = et * 16 + lo;
    f4 acc = {0.f, 0.f, 0.f, 0.f};
    for (int s = 0; s < 3; ++s) {
        int lsp = (rowA & 255) + s - 1;
        bool valid = (lsp >= 0) && (lsp < 256);
        int rs = rowA + s - 1;
        rs = rs < 0 ? 0 : (rs > NROWS - 1 ? NROWS - 1 : rs);
        const half_t* ab = A + (size_t)rs * EE;
        const half_t* wb = Wp + ((size_t)s * EE + eo) * EE;
#pragma unroll 4
        for (int ks = 0; ks < 16; ++ks) {
            h8 a = {0, 0, 0, 0, 0, 0, 0, 0};
            if (valid) a = *(const h8*)(ab + ks * 32 + quad * 8);
            h8 b = *(const h8*)(wb + ks * 32 + quad * 8);
            acc = __builtin_amdgcn_mfma_f32_16x16x32_f16(a, b, acc, 0, 0, 0);
        }
    }
    const int orow = nt * 64 + wv * 16 + quad * 4;
    const float bv = bias[eo];
#pragma unroll
    for (int r = 0; r < 4; ++r) out[(size_t)(orow + r) * EE + eo] = acc[r] + bv;
}

__global__ __launch_bounds__(256) void k_bnstats(const float* __restrict__ x,
                                                 float* __restrict__ mean,
                                                 float* __restrict__ rstd) {
    const int c = blockIdx.x;
    float s = 0.f, ss = 0.f;
    for (int n = threadIdx.x; n < NROWS; n += 256) {
        float v = x[(size_t)n * EE + c];
        s += v; ss += v * v;
    }
#pragma unroll
    for (int off = 32; off > 0; off >>= 1) { s += __shfl_down(s, off); ss += __shfl_down(ss, off); }
    __shared__ float as[4], ass[4];
    int wv = threadIdx.x >> 6;
    if ((threadIdx.x & 63) == 0) { as[wv] = s; ass[wv] = ss; }
    __syncthreads();
    if (threadIdx.x == 0) {
        float S = as[0] + as[1] + as[2] + as[3];
        float SS = ass[0] + ass[1] + ass[2] + ass[3];
        float m = S / (float)NROWS;
        float var = SS / (float)NROWS - m * m;
        mean[c] = m;
        rstd[c] = rsqrtf(var + 1e-5f);
    }
}

__global__ void k_bnapply(const float* __restrict__ x, const float* __restrict__ mean,
                          const float* __restrict__ rstd, const float* __restrict__ g,
                          const float* __restrict__ beta, half_t* __restrict__ out) {
    int idx = blockIdx.x * 256 + threadIdx.x;
    if (idx >= NROWS * EE) return;
    int c = idx & (EE - 1);
    float v = (x[idx] - mean[c]) * rstd[c] * g[c] + beta[c];
    out[idx] = (half_t)(v > 0.f ? v : 0.f);
}

__global__ void k_packrec(const float* __restrict__ src, half_t* __restrict__ dst,
                          int Hdim, int kshift, int total) {
    int idx = blockIdx.x * 256 + threadIdx.x;
    if (idx >= total) return;
    int p = idx >> kshift;
    int k = idx & ((1 << kshift) - 1);
    int he = p >> 2, g = p & 3;
    dst[idx] = (half_t)src[((size_t)g * Hdim + he) * (size_t)(1 << kshift) + k];
}

__global__ void k_bsumenc(const float* __restrict__ bf, const float* __restrict__ bhf,
                          const float* __restrict__ bb, const float* __restrict__ bhb,
                          float* __restrict__ bsum) {
    int p = blockIdx.x * 256 + threadIdx.x;
    if (p >= 4096) return;
    int dir = p >> 11, pp = p & 2047;
    int he = pp >> 2, g = pp & 3;
    int row = g * HH + he;
    bsum[p] = dir ? (bb[row] + bhb[row]) : (bf[row] + bhf[row]);
}

__global__ __launch_bounds__(256) void k_weff(const float* __restrict__ dwhh,
                                              const float* __restrict__ dwih,
                                              const float* __restrict__ projw,
                                              half_t* __restrict__ weff,
                                              half_t* __restrict__ w0) {
    int row = blockIdx.x;
    int k = blockIdx.y * 256 + threadIdx.x;
    float v = dwhh[(size_t)row * DD + k];
    float acc = v;
    for (int m = 0; m < MM; ++m) acc += dwih[(size_t)row * MM + m] * projw[(size_t)m * DD + k];
    int p = ((row & (DD - 1)) << 2) | (row >> 10);
    weff[(size_t)p * DD + k] = (half_t)acc;
    w0[(size_t)p * DD + k] = (half_t)v;
}

__global__ void k_bdec(const float* __restrict__ dbih, const float* __restrict__ dbhh,
                       const float* __restrict__ dwih, const float* __restrict__ projb,
                       float* __restrict__ beff, float* __restrict__ b0) {
    int p = blockIdx.x * 256 + threadIdx.x;
    if (p >= 4096) return;
    int he = p >> 2, g = p & 3;
    int row = g * DD + he;
    float bb = dbih[row] + dbhh[row];
    float acc = bb;
    for (int m = 0; m < MM; ++m) acc += dwih[(size_t)row * MM + m] * projb[m];
    b0[p] = bb;
    beff[p] = acc;
}

__global__ void k_cast(const float* __restrict__ src, half_t* __restrict__ dst, int n) {
    int idx = blockIdx.x * 256 + threadIdx.x;
    if (idx < n) dst[idx] = (half_t)src[idx];
}

__global__ void k_projg(const float* __restrict__ gw, half_t* __restrict__ pg) {
    int idx = blockIdx.x * 256 + threadIdx.x;
    if (idx >= 16 * DD) return;
    int row = idx >> 10, k = idx & (DD - 1);
    pg[idx] = (half_t)(row == 0 ? gw[k] : 0.f);
}

__global__ void k_mask(const int* __restrict__ lens, float* __restrict__ out) {
    int idx = blockIdx.x * 256 + threadIdx.x;
    if (idx >= B_ * TMEL) return;
    int b = idx / TMEL, t = idx - b * TMEL;
    out[MASK_OFF + idx] = (t > lens[b]) ? 1.f : 0.f;
}

// ---------------- persistent bidirectional encoder LSTM ----------------
// 64 blocks x 512 thr. dir=j>>5 (independent flag domains), sub=j&31 owns
// 16 h-elems. All-wave busy spin; nontemporal A/X loads; 4 acc chains.
__global__ __launch_bounds__(512, 2) void k_enc(const half_t* __restrict__ X,
                                                const half_t* __restrict__ wihp,
                                                const half_t* __restrict__ whhp,
                                                const float* __restrict__ bsum,
                                                const int* __restrict__ lens,
                                                half_t* __restrict__ henc,   // ring [RING_E][2][32][512]
                                                half_t* __restrict__ hd0,    // dec ring slot 0: [32][1024]
                                                float* __restrict__ cel,     // [32][1024]
                                                unsigned* __restrict__ flags) {  // [2][32*16]
    const int j = blockIdx.x;
    const int dir = j >> 5, sub = j & 31;
    const int tid = threadIdx.x;
    const int wv = tid >> 6, l = tid & 63, quad = l >> 4, lo = l & 15;
    const int rg = wv >> 1, bh = wv & 1;
    const int bfr = bh * 16 + lo;
    const int ue = tid >> 5, ub = tid & 31;
    unsigned* flg = flags + (size_t)dir * 512;
    const unsigned* fp = flg + (size_t)l * 16;

    __shared__ float s_g[32][65];
    __shared__ float s_c[16][32];
    __shared__ float s_h[16][32];
    __shared__ half_t s_hh[16][32];
    __shared__ int s_len[32];
    __shared__ unsigned s_rel;
    __shared__ float s_sink;

    if (tid < 32) s_len[tid] = lens[tid];
    if (tid == 0) s_rel = 0u;
    s_c[ue][ub] = 0.f;
    s_h[ue][ub] = 0.f;
    float burn = (float)tid * 1e-20f;

    const int pr = dir * 2048 + sub * 64 + rg * 16 + lo;
    const half_t* wih_b = wihp + (size_t)pr * 512 + quad * 8;
    const half_t* whh_b = whhp + (size_t)pr * 512 + quad * 8;
    const float bias_n = bsum[pr];

    int sp = 0, sn = HOP;
    __syncthreads();

    for (int t = 0; t < 256; ++t) {
        if (t >= 1) {
            if (wv == 0) {
                flag_wait(fp, l < 32, (unsigned)t, &burn);
                if (l == 0)
                    __hip_atomic_store(&s_rel, (unsigned)t, __ATOMIC_RELAXED,
                                       __HIP_MEMORY_SCOPE_WORKGROUP);
            } else {
                rel_spin(&s_rel, (unsigned)t, &burn);
            }
        }

        const int lb = s_len[bfr];
        int tt = (dir == 0) ? t : (lb - 1 - t);
        tt = tt < 0 ? 0 : tt;
        const half_t* xr = X + ((size_t)bfr * 256 + tt) * 512 + quad * 8;
        const half_t* ar = henc + (size_t)sp * 32768 + (size_t)dir * 16384
                           + (size_t)bfr * 512 + quad * 8;
        h8 ah[16], ax[16];
#pragma unroll
        for (int i = 0; i < 16; ++i) ah[i] = __builtin_nontemporal_load((const h8*)(ar + i * 32));
#pragma unroll
        for (int i = 0; i < 16; ++i) ax[i] = __builtin_nontemporal_load((const h8*)(xr + i * 32));

        f4 aB0 = {0.f, 0.f, 0.f, 0.f}, aB1 = {0.f, 0.f, 0.f, 0.f};
        f4 aA0 = {0.f, 0.f, 0.f, 0.f}, aA1 = {0.f, 0.f, 0.f, 0.f};
#pragma unroll
        for (int ks = 0; ks < 16; ks += 2) {
            aB0 = __builtin_amdgcn_mfma_f32_16x16x32_f16(ah[ks], *(const h8*)(whh_b + ks * 32), aB0, 0, 0, 0);
            aB1 = __builtin_amdgcn_mfma_f32_16x16x32_f16(ah[ks + 1], *(const h8*)(whh_b + (ks + 1) * 32), aB1, 0, 0, 0);
            aA0 = __builtin_amdgcn_mfma_f32_16x16x32_f16(ax[ks], *(const h8*)(wih_b + ks * 32), aA0, 0, 0, 0);
            aA1 = __builtin_amdgcn_mfma_f32_16x16x32_f16(ax[ks + 1], *(const h8*)(wih_b + (ks + 1) * 32), aA1, 0, 0, 0);
        }
        const int bm = bh * 16 + quad * 4, cm = rg * 16 + lo;
#pragma unroll
        for (int r = 0; r < 4; ++r)
            s_g[bm + r][cm] = aB0[r] + aB1[r] + aA0[r] + aA1[r] + bias_n;
        __syncthreads();
        {
            float gi = s_g[ub][ue * 4 + 0], gf = s_g[ub][ue * 4 + 1];
            float gg = s_g[ub][ue * 4 + 2], go = s_g[ub][ue * 4 + 3];
            float cn = sigm(gf) * s_c[ue][ub] + sigm(gi) * tanh_f(gg);
            float hn = sigm(go) * tanh_f(cn);
            if (t < s_len[ub]) { s_c[ue][ub] = cn; s_h[ue][ub] = hn; }
            s_hh[ue][ub] = (half_t)s_h[ue][ub];
        }
        __syncthreads();
        if (tid < 128 && t < 255) {
            int eq = tid >> 5, b2 = tid & 31;
            union { half_t h[4]; u64 u; } pk;
            pk.h[0] = s_hh[eq * 4 + 0][b2]; pk.h[1] = s_hh[eq * 4 + 1][b2];
            pk.h[2] = s_hh[eq * 4 + 2][b2]; pk.h[3] = s_hh[eq * 4 + 3][b2];
            st_wt64(henc + (size_t)sn * 32768 + (size_t)dir * 16384
                    + (size_t)b2 * 512 + sub * 16 + eq * 4, pk.u);
        }
        if (t < 255) {
            __builtin_amdgcn_s_waitcnt(0);
            __syncthreads();
            if (tid == 0) st_wt32(flg + (size_t)sub * 16, (unsigned)(t + 1));
            sp = sn; sn += HOP; if (sn >= RING_E) sn -= RING_E;
        }
    }
    hd0[(size_t)ub * 1024 + dir * 512 + sub * 16 + ue] = (half_t)s_h[ue][ub];
    cel[(size_t)ub * 1024 + dir * 512 + sub * 16 + ue] = s_c[ue][ub];
    if (burn == 1234.5678f) s_sink = burn;   // keep burn chain alive
}

// ---------------- persistent decoder LSTM ----------------
// 64 blocks x 512 thr, block j owns h-elems [16j,16j+16). All-wave busy spin,
// 4 acc chains, nontemporal ring loads, mel/gate output AFTER flag publish.
__global__ __launch_bounds__(512, 2) void k_dec(const half_t* __restrict__ Weff,
                                                const half_t* __restrict__ W0,
                                                const float* __restrict__ beff,
                                                const float* __restrict__ b0,
                                                const half_t* __restrict__ projwb,
                                                const half_t* __restrict__ projg,
                                                const float* __restrict__ projb,
                                                const float* __restrict__ gateb,
                                                const int* __restrict__ mlens,
                                                const float* __restrict__ cel,
                                                half_t* __restrict__ hd,   // ring [RING_D][32][1024]
                                                float* __restrict__ out,
                                                unsigned* __restrict__ flags) {  // [64*16]
    const int j = blockIdx.x;
    const int tid = threadIdx.x;
    const int wv = tid >> 6, l = tid & 63, quad = l >> 4, lo = l & 15;
    const int rg = wv >> 1, bh = wv & 1;
    const int bfr = bh * 16 + lo;
    const int ue = tid >> 5, ub = tid & 31;
    const unsigned* fp = flags + (size_t)l * 16;

    __shared__ float s_g[32][65];
    __shared__ float s_c[16][32];
    __shared__ half_t s_hh[16][32];
    __shared__ int s_len[32];
    __shared__ unsigned s_rel;
    __shared__ float s_sink;

    if (tid < 32) s_len[tid] = mlens[tid];
    if (tid == 0) s_rel = 0u;
    s_c[ue][ub] = cel[(size_t)ub * 1024 + j * 16 + ue];
    float burn = (float)tid * 1e-20f;

    const int pr = j * 64 + rg * 16 + lo;
    const float biasE = beff[pr], bias0 = b0[pr];
    const bool meld = (j < 8), gated = (j == 8);
    const bool duty = (meld || gated) && (rg == 0);
    const half_t* pw = nullptr;
    float biasP = 0.f;
    if (duty) {
        pw = (meld ? (projwb + (size_t)(j * 16 + lo) * 1024)
                   : (projg + (size_t)lo * 1024)) + quad * 8;
        biasP = meld ? projb[j * 16 + lo] : gateb[0];
    }
    const half_t* wbE = Weff + (size_t)pr * 1024 + quad * 8;
    const half_t* wb0 = W0 + (size_t)pr * 1024 + quad * 8;

    int sp = 0, sn = HOP;
    __syncthreads();

    for (int t = 1; t <= TMEL; ++t) {
        if (t >= 2) {
            if (wv == 0) {
                flag_wait(fp, 1, (unsigned)(t - 1), &burn);
                if (l == 0)
                    __hip_atomic_store(&s_rel, (unsigned)(t - 1), __ATOMIC_RELAXED,
                                       __HIP_MEMORY_SCOPE_WORKGROUP);
            } else {
                rel_spin(&s_rel, (unsigned)(t - 1), &burn);
            }
        }

        const half_t* ar = hd + (size_t)sp * 32768 + (size_t)bfr * 1024 + quad * 8;
        const half_t* wb = (t == 1) ? wb0 : wbE;
        h8 af[32];
#pragma unroll
        for (int i = 0; i < 32; ++i) af[i] = __builtin_nontemporal_load((const h8*)(ar + i * 32));

        f4 ac0 = {0.f, 0.f, 0.f, 0.f}, ac1 = {0.f, 0.f, 0.f, 0.f};
        f4 ac2 = {0.f, 0.f, 0.f, 0.f}, ac3 = {0.f, 0.f, 0.f, 0.f};
#pragma unroll
        for (int ks = 0; ks < 32; ks += 4) {
            ac0 = __builtin_amdgcn_mfma_f32_16x16x32_f16(af[ks], *(const h8*)(wb + ks * 32), ac0, 0, 0, 0);
            ac1 = __builtin_amdgcn_mfma_f32_16x16x32_f16(af[ks + 1], *(const h8*)(wb + (ks + 1) * 32), ac1, 0, 0, 0);
            ac2 = __builtin_amdgcn_mfma_f32_16x16x32_f16(af[ks + 2], *(const h8*)(wb + (ks + 2) * 32), ac2, 0, 0, 0);
            ac3 = __builtin_amdgcn_mfma_f32_16x16x32_f16(af[ks + 3], *(const h8*)(wb + (ks + 3) * 32), ac3, 0, 0, 0);
        }
        const float bn = (t == 1) ? bias0 : biasE;
        const int bm = bh * 16 + quad * 4, cm = rg * 16 + lo;
#pragma unroll
        for (int r = 0; r < 4; ++r)
            s_g[bm + r][cm] = ac0[r] + ac1[r] + ac2[r] + ac3[r] + bn;
        __syncthreads();
        {
            float gi = s_g[ub][ue * 4 + 0], gf = s_g[ub][ue * 4 + 1];
            float gg = s_g[ub][ue * 4 + 2], go = s_g[ub][ue * 4 + 3];
            float cn = sigm(gf) * s_c[ue][ub] + sigm(gi) * tanh_f(gg);
            s_c[ue][ub] = cn;
            s_hh[ue][ub] = (half_t)(sigm(go) * tanh_f(cn));
        }
        __syncthreads();
        if (tid < 128) {
            int eq = tid >> 5, b2 = tid & 31;
            union { half_t h[4]; u64 u; } pk;
            pk.h[0] = s_hh[eq * 4 + 0][b2]; pk.h[1] = s_hh[eq * 4 + 1][b2];
            pk.h[2] = s_hh[eq * 4 + 2][b2]; pk.h[3] = s_hh[eq * 4 + 3][b2];
            st_wt64(hd + (size_t)sn * 32768 + (size_t)b2 * 1024 + j * 16 + eq * 4, pk.u);
        }
        __builtin_amdgcn_s_waitcnt(0);
        __syncthreads();
        if (tid == 0) st_wt32((void*)(flags + (size_t)j * 16), (unsigned)t);

        // ---- output duty AFTER publish: off the inter-block critical path ----
        if (duty && t >= 2) {
            f4 am0 = {0.f, 0.f, 0.f, 0.f}, am1 = {0.f, 0.f, 0.f, 0.f};
#pragma unroll
            for (int ks = 0; ks < 32; ks += 2) {
                am0 = __builtin_amdgcn_mfma_f32_16x16x32_f16(af[ks], *(const h8*)(pw + ks * 32), am0, 0, 0, 0);
                am1 = __builtin_amdgcn_mfma_f32_16x16x32_f16(af[ks + 1], *(const h8*)(pw + (ks + 1) * 32), am1, 0, 0, 0);
            }
            am0[0] += am1[0]; am0[1] += am1[1]; am0[2] += am1[2]; am0[3] += am1[3];
            const int pos = t - 2;
            if (meld) {
#pragma unroll
                for (int r = 0; r < 4; ++r) {
                    int b = bh * 16 + quad * 4 + r;
                    float v = am0[r] + biasP;
                    if (pos > s_len[b]) v = 0.f;
                    __builtin_nontemporal_store(v,
                        &out[(size_t)b * (TMEL * MM) + (size_t)pos * MM + j * 16 + lo]);
                }
            } else if (lo == 0) {
#pragma unroll
                for (int r = 0; r < 4; ++r) {
                    int b = bh * 16 + quad * 4 + r;
                    float v = am0[r] + biasP;
                    if (pos > s_len[b]) v = 1000.f;
                    __builtin_nontemporal_store(v, &out[GATE_OFF + (size_t)b * TMEL + pos]);
                }
            }
        }
        sp = sn; sn += HOP; if (sn >= RING_D) sn -= RING_D;
    }
    // epilogue: outputs for pos 799 from h_800 (slot sp)
    if (wv == 0) {
        flag_wait(fp, 1, (unsigned)TMEL, &burn);
        if (l == 0)
            __hip_atomic_store(&s_rel, (unsigned)TMEL, __ATOMIC_RELAXED,
                               __HIP_MEMORY_SCOPE_WORKGROUP);
    } else {
        rel_spin(&s_rel, (unsigned)TMEL, &burn);
    }
    if (duty) {
        const half_t* ar = hd + (size_t)sp * 32768 + (size_t)bfr * 1024 + quad * 8;
        h8 af[32];
#pragma unroll
        for (int i = 0; i < 32; ++i) af[i] = __builtin_nontemporal_load((const h8*)(ar + i * 32));
        f4 am = {0.f, 0.f, 0.f, 0.f};
#pragma unroll
        for (int ks = 0; ks < 32; ++ks)
            am = __builtin_amdgcn_mfma_f32_16x16x32_f16(af[ks], *(const h8*)(pw + ks * 32), am, 0, 0, 0);
        if (meld) {
#pragma unroll
            for (int r = 0; r < 4; ++r) {
                int b = bh * 16 + quad * 4 + r;
                float v = am[r] + biasP;
                if (799 > s_len[b]) v = 0.f;
                out[(size_t)b * (TMEL * MM) + (size_t)799 * MM + j * 16 + lo] = v;
            }
        } else if (lo == 0) {
#pragma unroll
            for (int r = 0; r < 4; ++r) {
                int b = bh * 16 + quad * 4 + r;
                float v = am[r] + biasP;
                if (799 > s_len[b]) v = 1000.f;
                out[GATE_OFF + (size_t)b * TMEL + 799] = v;
            }
        }
    }
    if (burn == 1234.5678f) s_sink = burn;   // keep burn chain alive
}

// ---------------------------------------------------------------------------

extern "C" void kernel_launch(void* const* d_in, const int* in_sizes, int n_in,
                              void* d_out, int out_size, void* d_ws, size_t ws_size,
                              hipStream_t stream) {
    const int* x = (const int*)d_in[0];
    const int* tlens = (const int*)d_in[1];
    const int* mlens = (const int*)d_in[3];
    const float* emb = (const float*)d_in[4];
    const float* c1w = (const float*)d_in[5];
    const float* c1b = (const float*)d_in[6];
    const float* bn1g = (const float*)d_in[7];
    const float* bn1b = (const float*)d_in[8];
    const float* c2w = (const float*)d_in[9];
    const float* c2b = (const float*)d_in[10];
    const float* bn2g = (const float*)d_in[11];
    const float* bn2b = (const float*)d_in[12];
    const float* wihf = (const float*)d_in[13];
    const float* whhf = (const float*)d_in[14];
    const float* bihf = (const float*)d_in[15];
    const float* bhhf = (const float*)d_in[16];
    const float* wihb = (const float*)d_in[17];
    const float* whhb = (const float*)d_in[18];
    const float* bihb = (const float*)d_in[19];
    const float* bhhb = (const float*)d_in[20];
    const float* dwih = (const float*)d_in[21];
    const float* dwhh = (const float*)d_in[22];
    const float* dbih = (const float*)d_in[23];
    const float* dbhh = (const float*)d_in[24];
    const float* projw = (const float*)d_in[25];
    const float* projb = (const float*)d_in[26];
    const float* gatew = (const float*)d_in[27];
    const float* gateb = (const float*)d_in[28];
    float* out = (float*)d_out;
    char* ws = (char*)d_ws;

    unsigned* flags_dec = (unsigned*)(ws + WS_FLAGS);
    unsigned* flags_enc = (unsigned*)(ws + WS_FLAGS + 4096);
    half_t* henc = (half_t*)(ws + WS_HENC);
    half_t* hd = (half_t*)(ws + WS_HD);
    half_t* bufX = (half_t*)(ws + WS_BUFX);
    half_t* bufY = (half_t*)(ws + WS_BUFY);
    float* convf = (float*)(ws + WS_CONVF);
    half_t* weff = (half_t*)(ws + WS_WEFF);
    half_t* w0 = (half_t*)(ws + WS_W0);
    half_t* wp1 = (half_t*)(ws + WS_WP1);
    half_t* wp2 = (half_t*)(ws + WS_WP2);
    float* meanb = (float*)(ws + WS_MEAN);
    float* rstdb = (float*)(ws + WS_RSTD);
    half_t* wihp = (half_t*)(ws + WS_WIHP);
    half_t* whhp = (half_t*)(ws + WS_WHHP);
    float* bsum = (float*)(ws + WS_BSUM);
    float* beff = (float*)(ws + WS_BEFF);
    float* b0 = (float*)(ws + WS_B0);
    half_t* projwb = (half_t*)(ws + WS_PROJW);
    half_t* projg = (half_t*)(ws + WS_PROJG);
    float* cel = (float*)(ws + WS_CEL);

    // zero flag state + encoder ring slot 0
    hipMemsetAsync(d_ws, 0, (size_t)WS_ZERO_BYTES, stream);

    // front-end
    k_embed<<<NROWS, 256, 0, stream>>>(x, emb, bufX);
    k_packconvw<<<(3 * EE * EE + 255) / 256, 256, 0, stream>>>(c1w, wp1);
    k_conv<<<dim3(128, 32), 256, 0, stream>>>(bufX, wp1, c1b, convf);
    k_bnstats<<<EE, 256, 0, stream>>>(convf, meanb, rstdb);
    k_bnapply<<<(NROWS * EE) / 256, 256, 0, stream>>>(convf, meanb, rstdb, bn1g, bn1b, bufY);
    k_packconvw<<<(3 * EE * EE + 255) / 256, 256, 0, stream>>>(c2w, wp2);
    k_conv<<<dim3(128, 32), 256, 0, stream>>>(bufY, wp2, c2b, convf);
    k_bnstats<<<EE, 256, 0, stream>>>(convf, meanb, rstdb);
    k_bnapply<<<(NROWS * EE) / 256, 256, 0, stream>>>(convf, meanb, rstdb, bn2g, bn2b, bufX);

    // encoder weight prep
    const int encTot = 2048 * 512;
    k_packrec<<<(encTot + 255) / 256, 256, 0, stream>>>(wihf, wihp, HH, 9, encTot);
    k_packrec<<<(encTot + 255) / 256, 256, 0, stream>>>(wihb, wihp + encTot, HH, 9, encTot);
    k_packrec<<<(encTot + 255) / 256, 256, 0, stream>>>(whhf, whhp, HH, 9, encTot);
    k_packrec<<<(encTot + 255) / 256, 256, 0, stream>>>(whhb, whhp + encTot, HH, 9, encTot);
    k_bsumenc<<<16, 256, 0, stream>>>(bihf, bhhf, bihb, bhhb, bsum);

    // persistent bidirectional encoder (writes hd ring slot 0 + cel)
    k_enc<<<64, 512, 0, stream>>>(bufX, wihp, whhp, bsum, tlens, henc, hd, cel, flags_enc);

    // decoder weight prep (into retired convf region)
    k_weff<<<dim3(4096, 4), 256, 0, stream>>>(dwhh, dwih, projw, weff, w0);
    k_bdec<<<16, 256, 0, stream>>>(dbih, dbhh, dwih, projb, beff, b0);
    k_cast<<<(MM * DD + 255) / 256, 256, 0, stream>>>(projw, projwb, MM * DD);
    k_projg<<<(16 * DD + 255) / 256, 256, 0, stream>>>(gatew, projg);

    // persistent decoder
    k_dec<<<64, 512, 0, stream>>>(weff, w0, beff, b0, projwb, projg, projb, gateb,
                                  mlens, cel, hd, out, flags_dec);

    // mask output
    k_mask<<<(B_ * TMEL + 255) / 256, 256, 0, stream>>>(mlens, out);

    (void)in_sizes; (void)n_in; (void)out_size; (void)ws_size;
}